// Round 12
// baseline (53.907 us; speedup 1.0000x reference)
//
#include <hip/hip_runtime.h>
#include <math.h>

#define NQ   11
#define DIM  2048        // 2^11
#define NL   6

typedef float v2f __attribute__((ext_vector_type(2)));   // (re, im)

// GF(2)-linear swizzle for kernel 1 (R3-R10 proven conflict-free)
__host__ __device__ constexpr int swzA(int x) {
    return x ^ ((x >> 6) & 31) ^ ((x & 2) << 3) ^ ((x & 1) << 3);
}
// h = g^{-1} of the CNOT-chain perm g(o)=o^(o>>1): prefix-XOR from MSB
__host__ __device__ constexpr int hperm(int x) {
    return x ^ (x>>1) ^ (x>>2) ^ (x>>3) ^ (x>>4) ^ (x>>5)
             ^ (x>>6) ^ (x>>7) ^ (x>>8) ^ (x>>9) ^ (x>>10);
}

__device__ __forceinline__ float2 cfma2(float2 u, float2 a, float2 v, float2 b) {
    float2 r;
    r.x = u.x*a.x - u.y*a.y + v.x*b.x - v.y*b.y;
    r.y = u.x*a.y + u.y*a.x + v.x*b.y + v.y*b.x;
    return r;
}

// ---- forced VOP3P packed math; ALL operands are 64-bit VGPR pairs ----
__device__ __forceinline__ v2f pk_mul(v2f a, v2f b) {
    v2f d;
    asm("v_pk_mul_f32 %0, %1, %2" : "=v"(d) : "v"(a), "v"(b));
    return d;
}
__device__ __forceinline__ v2f pk_fma(v2f a, v2f b, v2f c) {
    v2f d;
    asm("v_pk_fma_f32 %0, %1, %2, %3" : "=v"(d) : "v"(a), "v"(b), "v"(c));
    return d;
}

// DPP lane-xor (VALU pipe): 177=xor1, 27=xor3, 0x141=xor7, 0x140=xor15
template<int CTRL>
__device__ __forceinline__ v2f dpp_xor(v2f v) {
    const int x = __builtin_amdgcn_update_dpp(
        0, __float_as_int(v.x), CTRL, 0xF, 0xF, true);
    const int y = __builtin_amdgcn_update_dpp(
        0, __float_as_int(v.y), CTRL, 0xF, 0xF, true);
    v2f r; r.x = __int_as_float(x); r.y = __int_as_float(y);
    return r;
}

// ================= kernel 1: all sample-independent work, 1 block ============
// (byte-for-byte the proven R5/R8/R10 version)
__global__ __launch_bounds__(256) void qnn_shared_kernel(
    const float* __restrict__ P,      // (NL, NQ, 3)
    float2* __restrict__ ws)          // out: 2048 float2, natural order
{
    __shared__ float2 lds[DIM];
    __shared__ float2 G[NL*NQ][4];
    const int t = threadIdx.x;        // 8 bits

    if (t < NL*NQ) {
        const float p0 = P[t*3+0], p1 = P[t*3+1], p2 = P[t*3+2];
        const float th = 0.5f*p1;
        const float c  = cosf(th), s = sinf(th);
        const float al = 0.5f*(p0+p2), be = 0.5f*(p0-p2);
        const float ca = cosf(al), sa = sinf(al);
        const float cb = cosf(be), sb = sinf(be);
        G[t][0] = make_float2( c*ca, -c*sa);
        G[t][1] = make_float2(-s*cb, -s*sb);
        G[t][2] = make_float2( s*cb, -s*sb);
        G[t][3] = make_float2( c*ca,  c*sa);
    }

    const int a0w = swzA(t);                          // X1 write (k<<8)
    const int a1b = swzA(((t>>5)<<8) | (t&31));       // X1 read / X2 write (k<<5)
    const int a2b = swzA(((t>>2)<<5) | (t&3));        // X2 read / X3 write (k<<2)
    const int a3b = swzA(t ^ (t>>1));                 // X3 perm-gather read
    const int natb = ((t>>2)<<5) | (t&3);             // ws natural-order base

    float2 a[8];
    #pragma unroll
    for (int k = 0; k < 8; ++k) a[k] = make_float2(0.f, 0.f);
    if (t == 0) a[0] = make_float2(1.f, 0.f);
    __syncthreads();   // G ready

    #define CG(g_, rb_) { \
        const float2 U00=G[g_][0], U01=G[g_][1], U10=G[g_][2], U11=G[g_][3]; \
        _Pragma("unroll") \
        for (int kk = 0; kk < 8; ++kk) if (!(kk & (rb_))) { \
            const float2 a0 = a[kk], a1 = a[kk|(rb_)]; \
            a[kk]       = cfma2(U00, a0, U01, a1); \
            a[kk|(rb_)] = cfma2(U10, a0, U11, a1); \
        } }

    #define SG(g_, m_, b_) { \
        const float2 ca_ = (b_) ? G[g_][3] : G[g_][0]; \
        const float2 cb_ = (b_) ? G[g_][2] : G[g_][1]; \
        _Pragma("unroll") \
        for (int kk = 0; kk < 8; ++kk) { \
            float2 p; \
            p.x = __shfl_xor(a[kk].x, m_); \
            p.y = __shfl_xor(a[kk].y, m_); \
            a[kk] = cfma2(ca_, a[kk], cb_, p); \
        } }

    for (int l = 0; l < NL; ++l) {
        const int g0 = l*NQ;
        CG(g0+0, 4) CG(g0+1, 2) CG(g0+2, 1)          // qubits 0,1,2 (bits 10,9,8)

        #pragma unroll
        for (int k = 0; k < 8; ++k) lds[a0w ^ swzA(k<<8)] = a[k];
        __syncthreads();
        #pragma unroll
        for (int k = 0; k < 8; ++k) a[k] = lds[a1b ^ swzA(k<<5)];
        __syncthreads();
        CG(g0+3, 4) CG(g0+4, 2) CG(g0+5, 1)          // qubits 3,4,5 (bits 7,6,5)

        #pragma unroll
        for (int k = 0; k < 8; ++k) lds[a1b ^ swzA(k<<5)] = a[k];
        __syncthreads();
        #pragma unroll
        for (int k = 0; k < 8; ++k) a[k] = lds[a2b ^ swzA(k<<2)];
        __syncthreads();
        CG(g0+6, 4) CG(g0+7, 2) CG(g0+8, 1)          // qubits 6,7,8 (bits 4,3,2)

        SG(g0+9, 2, (t>>1)&1)                        // qubit 9 (bit 1)
        SG(g0+10, 1, t&1)                            // qubit 10 (bit 0)

        if (l < NL-1) {
            #pragma unroll
            for (int k = 0; k < 8; ++k) lds[a2b ^ swzA(k<<2)] = a[k];
            __syncthreads();
            #pragma unroll
            for (int k = 0; k < 8; ++k)
                a[k] = lds[a3b ^ swzA((k<<8) ^ (k<<7))];   // src = g((k<<8)|t)
            __syncthreads();
        } else {
            #pragma unroll
            for (int k = 0; k < 8; ++k) ws[natb | (k<<2)] = a[k];
        }
    }
    #undef CG
    #undef SG
}

// ========= kernel 2: cell-paired layout + forced v_pk math, 8192 blocks ======
// R10 skeleton (proven): 128 thr x 8 cells; perm h-folded into X2 write;
// q6..q9 post-perm DPP butterflies. New: asm VOP3P gate math (pair operands),
// shfl-broadcast sincos (no gc LDS, no bar1), cell-major S3 with streamed st.
__global__ __launch_bounds__(128, 4) void qnn_last_kernel(
    const float* __restrict__ X,      // (B, NQ)
    const float4* __restrict__ S5c,   // shared state, 1024 cells, natural order
    float4* __restrict__ out4)        // (B, 1024) cells
{
    __shared__ float4 ldsc[DIM/2];    // 1024 cells = 16 KB
    const int b = blockIdx.x;
    const int t = threadIdx.x;        // 7 bits
    const int lane = t & 63;

    // L0 loads first (independent of sincos): a[2k+e] = amp (k<<8)|(t<<1)|e
    v2f a[16];
    #pragma unroll
    for (int k = 0; k < 8; ++k) {
        const float4 v = S5c[(k<<7) | t];
        a[2*k]   = (v2f){v.x, v.y};
        a[2*k+1] = (v2f){v.z, v.w};
    }

    // per-wave sincos: lane q holds (cos,sin) of x_q/2; broadcast via __shfl
    float vc = 1.f, vs = 0.f;
    if (lane < NQ) {
        const float tx = 0.5f * X[(size_t)b*NQ + lane];
        vc = cosf(tx); vs = sinf(tx);
    }

    // packed real RY on a-index bit rb_: per pair 2 pk_mul + 2 pk_fma
    #define RG(q_, rb_) { \
        const float c_ = __shfl(vc, q_), s_ = __shfl(vs, q_); \
        const v2f cc = {c_, c_}, sv = {s_, s_}, msv = {-s_, -s_}; \
        _Pragma("unroll") \
        for (int j = 0; j < 16; ++j) if (!(j & (rb_))) { \
            const v2f x0 = a[j], x1 = a[j|(rb_)]; \
            a[j]       = pk_fma(msv, x1, pk_mul(cc, x0)); \
            a[j|(rb_)] = pk_fma(sv,  x0, pk_mul(cc, x1)); \
        } }

    // S1: reg amp-bits {10,9,8} = k, {0} = e
    RG(0, 8) RG(1, 4) RG(2, 2) RG(10, 1)

    // X1 write: cell (k<<7)|t
    #pragma unroll
    for (int k = 0; k < 8; ++k)
        ldsc[(k<<7) | t] = make_float4(a[2*k].x, a[2*k].y, a[2*k+1].x, a[2*k+1].y);
    __syncthreads();   // bar: X1 w->r
    // X1 read: s = (t[6:4]<<8)|(k<<5)|(t[3:1]<<2)|(t0<<1)|e ; cell = s>>1
    const int cR = ((t>>4)<<7) | (t & 15);
    #pragma unroll
    for (int k = 0; k < 8; ++k) {
        const float4 v = ldsc[cR | (k<<4)];
        a[2*k]   = (v2f){v.x, v.y};
        a[2*k+1] = (v2f){v.z, v.w};
    }
    // S2: reg amp-bits {7,6,5} = k
    RG(3, 8) RG(4, 4) RG(5, 2)
    __syncthreads();   // bar: all X1 reads done before h-scattered writes

    // X2 write, perm-folded (R10-proven): amp s -> LDS slot h(s)
    {
        const int sB    = (((t>>4)&7)<<8) | (((t>>1)&7)<<2) | ((t&1)<<1);
        const int cellB = hperm(sB) >> 1;
        const int pt    = __popc(t) & 1;
        #pragma unroll
        for (int k = 0; k < 8; ++k) {
            const int cell = cellB ^ (hperm(k<<5) >> 1);   // constexpr k-part
            const bool sw  = (pt ^ (__popc(k) & 1)) != 0;
            const v2f lo = sw ? a[2*k+1] : a[2*k];
            const v2f hi = sw ? a[2*k]   : a[2*k+1];
            ldsc[cell] = make_float4(lo.x, lo.y, hi.x, hi.y);
        }
    }
    __syncthreads();   // bar: X2 w->r

    // S3 + store, cell-major: finish each cell, stream its store immediately.
    const float c6 = __shfl(vc, 6), s6 = __shfl(vs, 6);
    const float c7 = __shfl(vc, 7), s7 = __shfl(vs, 7);
    const float c8 = __shfl(vc, 8), s8 = __shfl(vs, 8);
    const float c9 = __shfl(vc, 9), s9 = __shfl(vs, 9);
    const v2f cc6 = {c6, c6}, gv6 = {(((t>>3)^(t>>4))&1) ? s6 : -s6,
                                     (((t>>3)^(t>>4))&1) ? s6 : -s6};
    const v2f cc7 = {c7, c7}, gv7 = {(((t>>2)^(t>>3))&1) ? s7 : -s7,
                                     (((t>>2)^(t>>3))&1) ? s7 : -s7};
    const v2f cc8 = {c8, c8}, gv8 = {(((t>>1)^(t>>2))&1) ? s8 : -s8,
                                     (((t>>1)^(t>>2))&1) ? s8 : -s8};
    const v2f cc9 = {c9, c9}, gv9 = {((t^(t>>1))&1) ? s9 : -s9,
                                     ((t^(t>>1))&1) ? s9 : -s9};

    #define CG1(CTRL_, cc_, gv_, A0, A1) { \
        const v2f o0 = A0, o1 = A1; \
        const v2f p0 = dpp_xor<CTRL_>(o1); \
        const v2f p1 = dpp_xor<CTRL_>(o0); \
        A0 = pk_fma(gv_, p0, pk_mul(cc_, o0)); \
        A1 = pk_fma(gv_, p1, pk_mul(cc_, o1)); }

    float4* o = out4 + (size_t)b * (DIM/2);
    #pragma unroll
    for (int k = 0; k < 8; ++k) {
        const float4 v = ldsc[(k<<7) | t];      // X2 read, linear
        v2f A0 = (v2f){v.x, v.y}, A1 = (v2f){v.z, v.w};
        CG1(0x140, cc6, gv6, A0, A1)            // q6: lane-xor15 + e-swap
        CG1(0x141, cc7, gv7, A0, A1)            // q7: lane-xor7  + e-swap
        CG1(27,    cc8, gv8, A0, A1)            // q8: lane-xor3  + e-swap
        CG1(177,   cc9, gv9, A0, A1)            // q9: lane-xor1  + e-swap
        o[(k<<7) | t] = make_float4(A0.x, A0.y, A1.x, A1.y);
    }
    #undef RG
    #undef CG1
}

extern "C" void kernel_launch(void* const* d_in, const int* in_sizes, int n_in,
                              void* d_out, int out_size, void* d_ws, size_t ws_size,
                              hipStream_t stream) {
    const float* X = (const float*)d_in[0];   // (B, NQ) float32
    const float* P = (const float*)d_in[1];   // (NL, NQ, 3) float32
    float2* ws  = (float2*)d_ws;              // 16 KB shared state (16B-aligned)
    const int B = in_sizes[0] / NQ;           // 8192
    qnn_shared_kernel<<<1, 256, 0, stream>>>(P, ws);
    qnn_last_kernel<<<B, 128, 0, stream>>>(X, (const float4*)ws, (float4*)d_out);
}